// Round 3
// baseline (725.177 us; speedup 1.0000x reference)
//
#include <hip/hip_runtime.h>

// Fused GQA attention layer for MI355X (gfx950).
// B=2 S=2048 E=4096 HQ=32 HKV=8 D=128 WINDOW=1024 SOFT_CAP=50 Q_PRE_ATTN=128
//
// R7: attn_fwd moved to 2-phase double-buffered K/V staging (T14/T3-min):
//     stage next tile into buf^1 BEFORE computing buf[cur]; ONE barrier per
//     KV tile (was 2 + full stage-latency exposure). LDS 72KB -> 2 blocks/CU.
//     gemm256: added optional pre-barrier lgkmcnt(8) hint in the 12-read
//     phases (P1/P5), per the 8-phase template.
// R6 results: 710us total; QKV gemm 226us (912 TF, MfmaUtil 39%, tail 1.5
//     rounds); attn est. ~200-245us latency-bound -> this round's target.
//
// Workspace layout (160 MiB, regions reused over time):
//   [0,        33.5M)  xb        -> later vtb
//   [33.5M,    83.9M)  WqkvT     -> later qb|kb|vb
//   [83.9M,   117.4M)  WoT       (persistent)
//   [117.4M,  167.8M)  qkv_raw   -> later attn

typedef unsigned short u16;
typedef unsigned int   u32;
typedef __bf16 bf16x8 __attribute__((ext_vector_type(8)));
typedef float  f32x4  __attribute__((ext_vector_type(4)));

typedef __attribute__((address_space(1))) void* gas_ptr;
typedef __attribute__((address_space(3))) void* las_ptr;

__device__ __forceinline__ void load_lds16(const void* g, void* l) {
  __builtin_amdgcn_global_load_lds((gas_ptr)g, (las_ptr)l, 16, 0, 0);
}

__device__ __forceinline__ u16 f2bf(float f) {
  u32 u = __builtin_bit_cast(u32, f);
  u += 0x7fffu + ((u >> 16) & 1u);   // RNE
  return (u16)(u >> 16);
}
__device__ __forceinline__ float bf2f(u16 h) {
  u32 u = ((u32)h) << 16;
  return __builtin_bit_cast(float, u);
}
// truncate-pack two fp32 -> bf16 pair (low = a, high = b)
__device__ __forceinline__ u32 pack_trunc(float a, float b) {
  return (__builtin_bit_cast(u32, a) >> 16) | (__builtin_bit_cast(u32, b) & 0xffff0000u);
}

// ---------------------------------------------------------------- cast x
__global__ __launch_bounds__(256) void cast_f32_bf16(const float* __restrict__ src,
                                                     u16* __restrict__ dst) {
  size_t i = ((size_t)blockIdx.x * 256 + threadIdx.x) * 8;
  float4 a = *(const float4*)(src + i);
  float4 b = *(const float4*)(src + i + 4);
  uint4 o;
  o.x = (u32)f2bf(a.x) | ((u32)f2bf(a.y) << 16);
  o.y = (u32)f2bf(a.z) | ((u32)f2bf(a.w) << 16);
  o.z = (u32)f2bf(b.x) | ((u32)f2bf(b.y) << 16);
  o.w = (u32)f2bf(b.z) | ((u32)f2bf(b.w) << 16);
  *(uint4*)(dst + i) = o;
}

// ------------------------------------------------- transpose-cast fp32->bf16
__global__ __launch_bounds__(256) void transpose_cast_f32_bf16(
    const float* __restrict__ src, u16* __restrict__ dst, int R, int C) {
  __shared__ float tile[32][33];
  const int tx = threadIdx.x & 31, ty = threadIdx.x >> 5;
  const int r0 = blockIdx.y * 32, c0 = blockIdx.x * 32;
#pragma unroll
  for (int i = 0; i < 4; ++i)
    tile[ty + i * 8][tx] = src[(size_t)(r0 + ty + i * 8) * C + (c0 + tx)];
  __syncthreads();
#pragma unroll
  for (int i = 0; i < 4; ++i)
    dst[(size_t)(c0 + ty + i * 8) * R + (r0 + tx)] = f2bf(tile[tx][ty + i * 8]);
}

// ------------------------------------------------- bf16 transpose for v planes
__global__ __launch_bounds__(256) void transpose_v(const u16* __restrict__ src,
                                                   u16* __restrict__ dst) {
  __shared__ u16 tile[32][34];
  const int plane = blockIdx.z;
  const u16* s = src + (size_t)plane * 2048 * 128;
  u16* d = dst + (size_t)plane * 2048 * 128;
  const int tx = threadIdx.x & 31, ty = threadIdx.x >> 5;
  const int r0 = blockIdx.x * 32, c0 = blockIdx.y * 32;
#pragma unroll
  for (int i = 0; i < 4; ++i)
    tile[ty + i * 8][tx] = s[(size_t)(r0 + ty + i * 8) * 128 + (c0 + tx)];
  __syncthreads();
#pragma unroll
  for (int i = 0; i < 4; ++i)
    d[(size_t)(c0 + ty + i * 8) * 2048 + (r0 + tx)] = tile[tx][ty + i * 8];
}

// ---------------------------------------------------------------- GEMM 256^2 8-phase
// C[M][N] = A[M][K] @ Bt[N][K]^T. Requires: M%256==0, N%256==0, K%128==0,
// grid = (M/256)*(N/256) with grid%8==0.
// LDS (u16 idx): buf b at b*32768; A-half h at +h*8192; B-half h at +16384+h*8192.
// Half-tile = 128 rows x 64 cols bf16, row = 64 u16; slot = 8 u16 (16B);
// physical slot = logical slot ^ (row & 7).
// Read schedule 12/4/8/0 per group is FORCED by the WAR ledger (stage order
// tb.A1 / t2.B0 / t2.B1 / t2.A0 at P1..P4): all B reads + Af0 must land in
// P1; A-kk1 reads must land by P3.

template <int MB>
__device__ __forceinline__ void mm16(f32x4 (&acc)[8][4], const bf16x8 (&af)[4],
                                     const bf16x8 (&bf)[4]) {
#pragma unroll
  for (int ii = 0; ii < 4; ++ii)
#pragma unroll
    for (int nf = 0; nf < 4; ++nf)
      acc[MB + ii][nf] =
          __builtin_amdgcn_mfma_f32_16x16x32_bf16(af[ii], bf[nf], acc[MB + ii][nf], 0, 0, 0);
}

template <int OUT_BF16>
__global__ __launch_bounds__(512, 2) void gemm256(const u16* __restrict__ A,
                                                  const u16* __restrict__ Bt,
                                                  void* __restrict__ Cout,
                                                  int N, int K, int ntx) {
  __shared__ __align__(16) u16 lds[65536];   // 128 KiB
  const int t = threadIdx.x, lane = t & 63, w = t >> 6;
  const int c = lane & 15, q = lane >> 4;
  const int wm = w >> 2, wn = w & 3;         // 2 x 4 wave grid, per-wave 128x64

  // bijective XCD swizzle (grid % 8 == 0)
  const int cpx = (int)gridDim.x >> 3;
  const int swz = ((int)blockIdx.x & 7) * cpx + ((int)blockIdx.x >> 3);
  const int bx = swz % ntx, by = swz / ntx;
  const int m0 = by << 8, n0 = bx << 8;

  // staging source offsets (u16 elements), source pre-swizzled so linear
  // global_load_lds dest yields swizzled LDS content
  u32 aoff[2][2], boff[2][2];
#pragma unroll
  for (int h = 0; h < 2; ++h)
#pragma unroll
    for (int j = 0; j < 2; ++j) {
      const int rowS = w * 16 + j * 8 + (lane >> 3);
      const int colE = ((lane & 7) ^ (rowS & 7)) * 8;
      aoff[h][j] = (u32)(m0 + h * 128 + rowS) * (u32)K + (u32)colE;
      boff[h][j] = (u32)(n0 + h * 128 + rowS) * (u32)K + (u32)colE;
    }
  const u32 stW = (u32)w * 1024u;  // wave's slice within a half-tile (u16 idx)

  // ds_read bases (u16 idx); kk=1 toggles slot bit 2 -> XOR 32
  const u32 sl0 = (u32)((q ^ (c & 7)) * 8);
  const u32 aR = (u32)(wm * 8192 + c * 64) + sl0;
  const u32 bR = (u32)(16384 + (wn >> 1) * 8192 + (wn & 1) * 4096 + c * 64) + sl0;

  f32x4 acc[8][4];
#pragma unroll
  for (int i2 = 0; i2 < 8; ++i2)
#pragma unroll
    for (int j2 = 0; j2 < 4; ++j2) acc[i2][j2] = (f32x4){0.f, 0.f, 0.f, 0.f};

  const int nt = K >> 6;  // K-tiles of 64; even

#define STG_A(bb, hh, kt)                                                \
  do {                                                                   \
    u16* d_ = &lds[(bb) * 32768u + (hh) * 8192u + stW];                  \
    load_lds16(A + (aoff[hh][0] + (u32)(kt) * 64u), d_);                 \
    load_lds16(A + (aoff[hh][1] + (u32)(kt) * 64u), d_ + 512);           \
  } while (0)
#define STG_B(bb, hh, kt)                                                \
  do {                                                                   \
    u16* d_ = &lds[(bb) * 32768u + 16384u + (hh) * 8192u + stW];         \
    load_lds16(Bt + (boff[hh][0] + (u32)(kt) * 64u), d_);                \
    load_lds16(Bt + (boff[hh][1] + (u32)(kt) * 64u), d_ + 512);          \
  } while (0)
#define RD4(dst, base)                                                   \
  do {                                                                   \
    const u16* p_ = &lds[(base)];                                        \
    dst[0] = *(const bf16x8*)(p_);                                       \
    dst[1] = *(const bf16x8*)(p_ + 1024);                                \
    dst[2] = *(const bf16x8*)(p_ + 2048);                                \
    dst[3] = *(const bf16x8*)(p_ + 3072);                                \
  } while (0)
#define BAR __builtin_amdgcn_s_barrier()
#define LGKM0 asm volatile("s_waitcnt lgkmcnt(0)" ::: "memory")
#define LGKM8 asm volatile("s_waitcnt lgkmcnt(8)" ::: "memory")
#define VM6 asm volatile("s_waitcnt vmcnt(6)" ::: "memory")
#define PRIO1 __builtin_amdgcn_s_setprio(1)
#define PRIO0 __builtin_amdgcn_s_setprio(0)

  // ---- prologue: stage tile0 {B0,B1,A0,A1} + tile1 {B0,B1,A0}; keep 3 in flight
  STG_B(0, 0, 0);
  STG_B(0, 1, 0);
  STG_A(0, 0, 0);
  STG_A(0, 1, 0);
  STG_B(1, 0, 1);
  STG_B(1, 1, 1);
  STG_A(1, 0, 1);
  VM6;   // tile0 fully resident; tile1 {B0,B1,A0} in flight
  BAR;

  bf16x8 Bf0[4], Bf1[4], Af0[4], Af1[4];

  for (int i = 0; i < (nt >> 1); ++i) {
    const int tb = 2 * i + 1;
    int t2 = 2 * i + 2; if (t2 >= nt) t2 -= nt;   // wrapped tail stages are
    int t3 = 2 * i + 3; if (t3 >= nt) t3 -= nt;   // garbage-but-harmless

    // ======== group 1: tile 2i from buf0 ========
    // P1: reads 12 (all B kk0+kk1, A m0-3 kk0); stage tb.A1 -> buf1.A1
    RD4(Bf0, bR);
    RD4(Bf1, bR ^ 32u);
    RD4(Af0, aR);
    STG_A(1, 1, tb);
    LGKM8;
    BAR; LGKM0;
    PRIO1; mm16<0>(acc, Af0, Bf0); PRIO0;
    BAR;
    // P2: reads A m4-7 kk0; stage t2.B0 -> buf0.B0 (B reads all done in P1)
    RD4(Af1, aR + 4096u);
    STG_B(0, 0, t2);
    BAR; LGKM0;
    PRIO1; mm16<4>(acc, Af1, Bf0); PRIO0;
    BAR;
    // P3: reads A m0-7 kk1; stage t2.B1 -> buf0.B1
    RD4(Af0, aR ^ 32u);
    RD4(Af1, (aR + 4096u) ^ 32u);
    STG_B(0, 1, t2);
    BAR; LGKM0;
    PRIO1; mm16<0>(acc, Af0, Bf1); PRIO0;
    BAR;
    // P4: no reads; stage t2.A0 -> buf0.A0 (A reads done by P3); counted vmcnt
    STG_A(0, 0, t2);
    VM6;  // retires tile tb completely (B0,B1,A0,A1); t2 {B0,B1,A0} in flight
    BAR;
    PRIO1; mm16<4>(acc, Af1, Bf1); PRIO0;
    BAR;

    // ======== group 2: tile 2i+1 from buf1 ========
    // P5
    RD4(Bf0, 32768u + bR);
    RD4(Bf1, (32768u + bR) ^ 32u);
    RD4(Af0, 32768u + aR);
    STG_A(0, 1, t2);
    LGKM8;
    BAR; LGKM0;
    PRIO1; mm16<0>(acc, Af0, Bf0); PRIO0;
    BAR;
    // P6
    RD4(Af1, 32768u + aR + 4096u);
    STG_B(1, 0, t3);
    BAR; LGKM0;
    PRIO1; mm16<4>(acc, Af1, Bf0); PRIO0;
    BAR;
    // P7
    RD4(Af0, (32768u + aR) ^ 32u);
    RD4(Af1, (32768u + aR + 4096u) ^ 32u);
    STG_B(1, 1, t3);
    BAR; LGKM0;
    PRIO1; mm16<0>(acc, Af0, Bf1); PRIO0;
    BAR;
    // P8
    STG_A(1, 0, t3);
    VM6;  // retires tile t2 completely; t3 {B0,B1,A0} in flight
    BAR;
    PRIO1; mm16<4>(acc, Af1, Bf1); PRIO0;
    BAR;
  }

  asm volatile("s_waitcnt vmcnt(0)" ::: "memory");  // drain wrapped tail stages

#undef STG_A
#undef STG_B
#undef RD4
#undef BAR
#undef LGKM0
#undef LGKM8
#undef VM6
#undef PRIO1
#undef PRIO0

  const int rb0 = m0 + wm * 128 + q * 4;
  const int cb0 = n0 + wn * 64 + c;
#pragma unroll
  for (int mf = 0; mf < 8; ++mf)
#pragma unroll
    for (int nf = 0; nf < 4; ++nf) {
      const size_t base = (size_t)(rb0 + mf * 16) * N + (cb0 + nf * 16);
#pragma unroll
      for (int r = 0; r < 4; ++r) {
        if (OUT_BF16)
          ((u16*)Cout)[base + (size_t)r * N] = f2bf(acc[mf][nf][r]);
        else
          ((float*)Cout)[base + (size_t)r * N] = acc[mf][nf][r];
      }
    }
}

// ---------------------------------------------------------------- qkv postprocess
__global__ __launch_bounds__(256) void qkv_post(const u16* __restrict__ raw,
                                                u16* __restrict__ qb,
                                                u16* __restrict__ kb,
                                                u16* __restrict__ vb) {
  const int t = threadIdx.x, lane = t & 63, w = t >> 6;
  const int idx = blockIdx.x * 4 + w;
  const int row = idx / 48, hh = idx - row * 48;
  const int b = row >> 11, pos = row & 2047;
  const u16* base = raw + (size_t)row * 6144 + hh * 128;
  const u16 r1 = base[lane], r2 = base[lane + 64];

  if (hh >= 40) {
    u16* dst = vb + ((size_t)((b * 8 + (hh - 40)) * 2048 + pos)) * 128;
    dst[lane] = r1;
    dst[lane + 64] = r2;
    return;
  }
  float v1 = bf2f(r1), v2 = bf2f(r2);
  float ss = v1 * v1 + v2 * v2;
#pragma unroll
  for (int off = 32; off >= 1; off >>= 1) ss += __shfl_xor(ss, off);
  const float rn = rsqrtf(ss * (1.0f / 128.0f) + 1e-6f);
  const float n1 = v1 * rn, n2 = v2 * rn;
  const float fr = exp2f(-(float)lane * 0.20762050593046f);  // 10000^(-lane/64)
  const float ang = (float)pos * fr;
  float sn, cs;
  sincosf(ang, &sn, &cs);
  float o1 = n1 * cs - n2 * sn;
  float o2 = n2 * cs + n1 * sn;
  u16* dst;
  if (hh < 32) {
    const float as_ = logf(floorf((float)(pos + 1) * (1.0f / 8192.0f)) + 1.0f) * 0.1f + 1.0f;
    const float sc = 0.088388347648318447f * as_;  // 128^-0.5 * attn_scale
    o1 *= sc;
    o2 *= sc;
    dst = qb + ((size_t)((b * 32 + hh) * 2048 + pos)) * 128;
  } else {
    dst = kb + ((size_t)((b * 8 + (hh - 32)) * 2048 + pos)) * 128;
  }
  dst[lane] = f2bf(o1);
  dst[lane + 64] = f2bf(o2);
}

// ---------------------------------------------------------------- flash attention
// Block: one (b, hq, 64-query tile); 4 waves; each wave owns 16 queries.
// R7: double-buffered K/V staging -- stage tile t+1 into buf^1 BEFORE
// computing buf[cur]; one __syncthreads per tile (drains stage vmcnt +
// guards WAR: buf[cur]'s reads retire before next iter re-stages it).
__global__ __launch_bounds__(256, 4) void attn_fwd(const u16* __restrict__ qb,
                                                   const u16* __restrict__ kb,
                                                   const u16* __restrict__ vtb,
                                                   u16* __restrict__ attn) {
  __shared__ __align__(16) u16 Ks[2][64 * 128];    // [buf][key][d], chunk-swizzled
  __shared__ __align__(16) u16 VTs[2][128 * 64];   // [buf][d][key], chunk-swizzled
  __shared__ __align__(16) u16 Ps[4][16 * 64];     // per-wave [query][key], swizzled

  const int t = threadIdx.x, lane = t & 63, w = t >> 6;
  const int c = lane & 15, quad = lane >> 4;
  const int q0 = blockIdx.x * 64;
  const int bh = blockIdx.y;
  const int b = bh >> 5, hq = bh & 31;
  const int kvp = b * 8 + (hq >> 2);
  const u16* qp = qb + (size_t)bh * (2048 * 128);
  const u16* kp = kb + (size_t)kvp * (2048 * 128);
  const u16* vp = vtb + (size_t)kvp * (128 * 2048);
  u16* Psw = &Ps[w][0];

  bf16x8 qf[4];
  {
    const u16* qrow = qp + (size_t)(q0 + w * 16 + c) * 128 + quad * 8;
#pragma unroll
    for (int ks = 0; ks < 4; ++ks) qf[ks] = *(const bf16x8*)(qrow + ks * 32);
  }

  f32x4 oacc[8];
#pragma unroll
  for (int j = 0; j < 8; ++j)
#pragma unroll
    for (int r = 0; r < 4; ++r) oacc[j][r] = 0.0f;
  float lsum = 0.0f;

  const int i_glob = q0 + w * 16 + c;

  int t0 = q0 - 1023;
  if (t0 < 0) t0 = 0;
  t0 = (t0 >> 6) << 6;

#define STAGE_KV(nb, kvbase)                                                   \
  do {                                                                         \
    const int row_in_ = lane >> 4, ch_ = lane & 15;                            \
    _Pragma("unroll")                                                          \
    for (int i_ = 0; i_ < 4; ++i_) {                                           \
      const int row_ = w * 4 + i_ * 16 + row_in_;                              \
      const int g_ = ch_ ^ (row_ & 15);                                        \
      load_lds16(kp + (size_t)((kvbase) + row_) * 128 + g_ * 8,                \
                 &Ks[nb][(w * 4 + i_ * 16) * 128]);                            \
    }                                                                          \
    const int drow_ = lane >> 3, ch8_ = lane & 7;                              \
    _Pragma("unroll")                                                          \
    for (int i_ = 0; i_ < 4; ++i_) {                                           \
      const int dd_ = w * 8 + i_ * 32 + drow_;                                 \
      const int g_ = ch8_ ^ (dd_ & 7);                                         \
      load_lds16(vp + (size_t)dd_ * 2048 + (kvbase) + g_ * 8,                  \
                 &VTs[nb][(w * 8 + i_ * 32) * 64]);                            \
    }                                                                          \
  } while (0)

  // prologue: stage first tile into buf0
  STAGE_KV(0, t0);
  __syncthreads();

  int cur = 0;
  for (int kv0 = t0; kv0 <= q0; kv0 += 64) {
    // prefetch next tile into the other buffer (block-uniform guard)
    if (kv0 + 64 <= q0) STAGE_KV(cur ^ 1, kv0 + 64);

    const u16* Kc = &Ks[cur][0];
    const u16* Vc = &VTs[cur][0];

    // ---- S^T = K * Q^T : wave computes 64 keys x 16 queries
    f32x4 sacc[4];
#pragma unroll
    for (int im = 0; im < 4; ++im)
#pragma unroll
      for (int r = 0; r < 4; ++r) sacc[im][r] = 0.0f;

#pragma unroll
    for (int ks = 0; ks < 4; ++ks) {
#pragma unroll
      for (int im = 0; im < 4; ++im) {
        const int key = im * 16 + c;
        const int ch = (ks * 4 + quad) ^ c;  // key & 15 == c
        const bf16x8 af = *(const bf16x8*)&Kc[key * 128 + ch * 8];
        sacc[im] = __builtin_amdgcn_mfma_f32_16x16x32_bf16(af, qf[ks], sacc[im], 0, 0, 0);
      }
    }

    const bool need_mask = (kv0 == q0) || (q0 - kv0 >= 961);
#pragma unroll
    for (int im = 0; im < 4; ++im) {
      float pv[4];
#pragma unroll
      for (int r = 0; r < 4; ++r) {
        const float s = sacc[im][r];
        const float u = s * s;
        // 50*tanh(s/50) = s*(1 - u/7500 + 2u^2/9.375e7), |s|<=11.4
        const float cap = s * (1.0f + u * (-1.3333333e-4f + u * 2.1333333e-8f));
        pv[r] = __expf(cap);
      }
      if (need_mask) {
        const int j_base = kv0 + im * 16 + quad * 4;
#pragma unroll
        for (int r = 0; r < 4; ++r) {
          const int j_glob = j_base + r;
          if (!((j_glob <= i_glob) && (i_glob - j_glob < 1024))) pv[r] = 0.0f;
        }
      }
      lsum += (pv[0] + pv[1]) + (pv[2] + pv[3]);
      uint2 pk;
      pk.x = pack_trunc(pv[0], pv[1]);
      pk.y = pack_trunc(pv[2], pv[3]);
      *(uint2*)&Psw[c * 64 + ((im * 2 + (quad >> 1)) ^ (c & 7)) * 8 + (quad & 1) * 4] = pk;
    }

    // ---- PV: A-frag = Psw[c][ks*32+quad*8..+7] (chunk ks*4+quad, slot ^(c&7))
#pragma unroll
    for (int ks = 0; ks < 2; ++ks) {
      const bf16x8 pf = *(const bf16x8*)&Psw[c * 64 + ((ks * 4 + quad) ^ (c & 7)) * 8];
#pragma unroll
      for (int jn = 0; jn < 8; ++jn) {
        const int dd = jn * 16 + c;
        const int ch = (ks * 4 + quad) ^ (c & 7);  // dd & 7 == c & 7
        const bf16x8 vf = *(const bf16x8*)&Vc[dd * 64 + ch * 8];
        oacc[jn] = __builtin_amdgcn_mfma_f32_16x16x32_bf16(pf, vf, oacc[jn], 0, 0, 0);
      }
    }

    __syncthreads();  // stage of next tile drained; buf[cur] reads retired
    cur ^= 1;
  }
#undef STAGE_KV

  // ---- normalize + store (cross-quad shuffle reduce; no LDS)
  float lt = lsum;
  lt += __shfl_xor(lt, 16);
  lt += __shfl_xor(lt, 32);       // all lanes: total for query c
  float rl[4];
#pragma unroll
  for (int r = 0; r < 4; ++r)
    rl[r] = __builtin_amdgcn_rcpf(__shfl(lt, quad * 4 + r));

  const size_t obase = ((size_t)(b * 2048 + q0 + w * 16)) * 4096 + hq * 128;
#pragma unroll
  for (int jn = 0; jn < 8; ++jn) {
#pragma unroll
    for (int r = 0; r < 4; ++r) {
      const int q_in = quad * 4 + r;
      attn[obase + (size_t)q_in * 4096 + jn * 16 + c] = f2bf(oacc[jn][r] * rl[r]);
    }
  }
}

// ---------------------------------------------------------------- launch
extern "C" void kernel_launch(void* const* d_in, const int* in_sizes, int n_in,
                              void* d_out, int out_size, void* d_ws, size_t ws_size,
                              hipStream_t stream) {
  (void)in_sizes; (void)n_in; (void)out_size; (void)ws_size;
  const float* x  = (const float*)d_in[0];
  const float* Wq = (const float*)d_in[1];
  const float* Wk = (const float*)d_in[2];
  const float* Wv = (const float*)d_in[3];
  const float* Wo = (const float*)d_in[4];
  float* out = (float*)d_out;
  char* ws = (char*)d_ws;

  u16* xb    = (u16*)(ws + 0);
  u16* vtb   = (u16*)(ws + 0);
  u16* WqkvT = (u16*)(ws + 33554432ULL);
  u16* qb    = (u16*)(ws + 33554432ULL);
  u16* kb    = (u16*)(ws + 67108864ULL);
  u16* vb    = (u16*)(ws + 75497472ULL);
  u16* WoT   = (u16*)(ws + 83886080ULL);
  u16* qkvr  = (u16*)(ws + 117440512ULL);
  u16* attnb = (u16*)(ws + 117440512ULL);

  cast_f32_bf16<<<8192, 256, 0, stream>>>(x, xb);
  transpose_cast_f32_bf16<<<dim3(128, 128), 256, 0, stream>>>(Wq, WqkvT, 4096, 4096);
  transpose_cast_f32_bf16<<<dim3(32, 128), 256, 0, stream>>>(Wk, WqkvT + (size_t)4096 * 4096, 4096, 1024);
  transpose_cast_f32_bf16<<<dim3(32, 128), 256, 0, stream>>>(Wv, WqkvT + (size_t)5120 * 4096, 4096, 1024);
  transpose_cast_f32_bf16<<<dim3(128, 128), 256, 0, stream>>>(Wo, WoT, 4096, 4096);

  // QKV: M=4096, N=6144, K=4096 -> 16x24 = 384 tiles (384 % 8 == 0)
  gemm256<1><<<dim3(384), 512, 0, stream>>>(xb, WqkvT, (void*)qkvr, 6144, 4096, 24);
  qkv_post<<<49152, 256, 0, stream>>>(qkvr, qb, kb, vb);
  transpose_v<<<dim3(64, 4, 16), 256, 0, stream>>>(vb, vtb);
  attn_fwd<<<dim3(32, 64), 256, 0, stream>>>(qb, kb, vtb, attnb);
  // Out: M=4096, N=4096, K=4096 -> 16x16 = 256 tiles (256 % 8 == 0)
  gemm256<0><<<dim3(256), 512, 0, stream>>>(attnb, WoT, (void*)out, 4096, 4096, 16);
}

// Round 4
// 722.360 us; speedup vs baseline: 1.0039x; 1.0039x over previous
//
#include <hip/hip_runtime.h>

// Fused GQA attention layer for MI355X (gfx950).
// B=2 S=2048 E=4096 HQ=32 HKV=8 D=128 WINDOW=1024 SOFT_CAP=50 Q_PRE_ATTN=128
//
// R8: attn_fwd = KVBLK=32 double-buffer: K/V dbuf 32KB + Ps 4KB = 36KB LDS
//     -> KEEPS 4 blocks/CU (R7's dbuf cost occupancy: 72KB -> 2/CU, +15us).
//     One barrier per KV tile; stage of tile t+1 issued before compute of t
//     (R7-proven ledger). Slot swizzle (r&3)^((r>>2)&3) for 4-slot rows
//     (V^T, P); K keeps R6's 16-chunk swizzle. XCD-contiguous q-tile map.
//     gemm256 unchanged from R7 (226us, measured == R6).
//
// Workspace layout (160 MiB, regions reused over time):
//   [0,        33.5M)  xb        -> later vtb
//   [33.5M,    83.9M)  WqkvT     -> later qb|kb|vb
//   [83.9M,   117.4M)  WoT       (persistent)
//   [117.4M,  167.8M)  qkv_raw   -> later attn

typedef unsigned short u16;
typedef unsigned int   u32;
typedef __bf16 bf16x8 __attribute__((ext_vector_type(8)));
typedef float  f32x4  __attribute__((ext_vector_type(4)));

typedef __attribute__((address_space(1))) void* gas_ptr;
typedef __attribute__((address_space(3))) void* las_ptr;

__device__ __forceinline__ void load_lds16(const void* g, void* l) {
  __builtin_amdgcn_global_load_lds((gas_ptr)g, (las_ptr)l, 16, 0, 0);
}

__device__ __forceinline__ u16 f2bf(float f) {
  u32 u = __builtin_bit_cast(u32, f);
  u += 0x7fffu + ((u >> 16) & 1u);   // RNE
  return (u16)(u >> 16);
}
__device__ __forceinline__ float bf2f(u16 h) {
  u32 u = ((u32)h) << 16;
  return __builtin_bit_cast(float, u);
}
// truncate-pack two fp32 -> bf16 pair (low = a, high = b)
__device__ __forceinline__ u32 pack_trunc(float a, float b) {
  return (__builtin_bit_cast(u32, a) >> 16) | (__builtin_bit_cast(u32, b) & 0xffff0000u);
}

// ---------------------------------------------------------------- cast x
__global__ __launch_bounds__(256) void cast_f32_bf16(const float* __restrict__ src,
                                                     u16* __restrict__ dst) {
  size_t i = ((size_t)blockIdx.x * 256 + threadIdx.x) * 8;
  float4 a = *(const float4*)(src + i);
  float4 b = *(const float4*)(src + i + 4);
  uint4 o;
  o.x = (u32)f2bf(a.x) | ((u32)f2bf(a.y) << 16);
  o.y = (u32)f2bf(a.z) | ((u32)f2bf(a.w) << 16);
  o.z = (u32)f2bf(b.x) | ((u32)f2bf(b.y) << 16);
  o.w = (u32)f2bf(b.z) | ((u32)f2bf(b.w) << 16);
  *(uint4*)(dst + i) = o;
}

// ------------------------------------------------- transpose-cast fp32->bf16
__global__ __launch_bounds__(256) void transpose_cast_f32_bf16(
    const float* __restrict__ src, u16* __restrict__ dst, int R, int C) {
  __shared__ float tile[32][33];
  const int tx = threadIdx.x & 31, ty = threadIdx.x >> 5;
  const int r0 = blockIdx.y * 32, c0 = blockIdx.x * 32;
#pragma unroll
  for (int i = 0; i < 4; ++i)
    tile[ty + i * 8][tx] = src[(size_t)(r0 + ty + i * 8) * C + (c0 + tx)];
  __syncthreads();
#pragma unroll
  for (int i = 0; i < 4; ++i)
    dst[(size_t)(c0 + ty + i * 8) * R + (r0 + tx)] = f2bf(tile[tx][ty + i * 8]);
}

// ------------------------------------------------- bf16 transpose for v planes
__global__ __launch_bounds__(256) void transpose_v(const u16* __restrict__ src,
                                                   u16* __restrict__ dst) {
  __shared__ u16 tile[32][34];
  const int plane = blockIdx.z;
  const u16* s = src + (size_t)plane * 2048 * 128;
  u16* d = dst + (size_t)plane * 2048 * 128;
  const int tx = threadIdx.x & 31, ty = threadIdx.x >> 5;
  const int r0 = blockIdx.x * 32, c0 = blockIdx.y * 32;
#pragma unroll
  for (int i = 0; i < 4; ++i)
    tile[ty + i * 8][tx] = s[(size_t)(r0 + ty + i * 8) * 128 + (c0 + tx)];
  __syncthreads();
#pragma unroll
  for (int i = 0; i < 4; ++i)
    d[(size_t)(c0 + ty + i * 8) * 2048 + (r0 + tx)] = tile[tx][ty + i * 8];
}

// ---------------------------------------------------------------- GEMM 256^2 8-phase
// C[M][N] = A[M][K] @ Bt[N][K]^T. Requires: M%256==0, N%256==0, K%128==0,
// grid = (M/256)*(N/256) with grid%8==0.
// LDS (u16 idx): buf b at b*32768; A-half h at +h*8192; B-half h at +16384+h*8192.
// Half-tile = 128 rows x 64 cols bf16, row = 64 u16; slot = 8 u16 (16B);
// physical slot = logical slot ^ (row & 7).
// Read schedule 12/4/8/0 per group is FORCED by the WAR ledger (stage order
// tb.A1 / t2.B0 / t2.B1 / t2.A0 at P1..P4): all B reads + Af0 must land in
// P1; A-kk1 reads must land by P3.

template <int MB>
__device__ __forceinline__ void mm16(f32x4 (&acc)[8][4], const bf16x8 (&af)[4],
                                     const bf16x8 (&bf)[4]) {
#pragma unroll
  for (int ii = 0; ii < 4; ++ii)
#pragma unroll
    for (int nf = 0; nf < 4; ++nf)
      acc[MB + ii][nf] =
          __builtin_amdgcn_mfma_f32_16x16x32_bf16(af[ii], bf[nf], acc[MB + ii][nf], 0, 0, 0);
}

template <int OUT_BF16>
__global__ __launch_bounds__(512, 2) void gemm256(const u16* __restrict__ A,
                                                  const u16* __restrict__ Bt,
                                                  void* __restrict__ Cout,
                                                  int N, int K, int ntx) {
  __shared__ __align__(16) u16 lds[65536];   // 128 KiB
  const int t = threadIdx.x, lane = t & 63, w = t >> 6;
  const int c = lane & 15, q = lane >> 4;
  const int wm = w >> 2, wn = w & 3;         // 2 x 4 wave grid, per-wave 128x64

  // bijective XCD swizzle (grid % 8 == 0)
  const int cpx = (int)gridDim.x >> 3;
  const int swz = ((int)blockIdx.x & 7) * cpx + ((int)blockIdx.x >> 3);
  const int bx = swz % ntx, by = swz / ntx;
  const int m0 = by << 8, n0 = bx << 8;

  // staging source offsets (u16 elements), source pre-swizzled so linear
  // global_load_lds dest yields swizzled LDS content
  u32 aoff[2][2], boff[2][2];
#pragma unroll
  for (int h = 0; h < 2; ++h)
#pragma unroll
    for (int j = 0; j < 2; ++j) {
      const int rowS = w * 16 + j * 8 + (lane >> 3);
      const int colE = ((lane & 7) ^ (rowS & 7)) * 8;
      aoff[h][j] = (u32)(m0 + h * 128 + rowS) * (u32)K + (u32)colE;
      boff[h][j] = (u32)(n0 + h * 128 + rowS) * (u32)K + (u32)colE;
    }
  const u32 stW = (u32)w * 1024u;  // wave's slice within a half-tile (u16 idx)

  // ds_read bases (u16 idx); kk=1 toggles slot bit 2 -> XOR 32
  const u32 sl0 = (u32)((q ^ (c & 7)) * 8);
  const u32 aR = (u32)(wm * 8192 + c * 64) + sl0;
  const u32 bR = (u32)(16384 + (wn >> 1) * 8192 + (wn & 1) * 4096 + c * 64) + sl0;

  f32x4 acc[8][4];
#pragma unroll
  for (int i2 = 0; i2 < 8; ++i2)
#pragma unroll
    for (int j2 = 0; j2 < 4; ++j2) acc[i2][j2] = (f32x4){0.f, 0.f, 0.f, 0.f};

  const int nt = K >> 6;  // K-tiles of 64; even

#define STG_A(bb, hh, kt)                                                \
  do {                                                                   \
    u16* d_ = &lds[(bb) * 32768u + (hh) * 8192u + stW];                  \
    load_lds16(A + (aoff[hh][0] + (u32)(kt) * 64u), d_);                 \
    load_lds16(A + (aoff[hh][1] + (u32)(kt) * 64u), d_ + 512);           \
  } while (0)
#define STG_B(bb, hh, kt)                                                \
  do {                                                                   \
    u16* d_ = &lds[(bb) * 32768u + 16384u + (hh) * 8192u + stW];         \
    load_lds16(Bt + (boff[hh][0] + (u32)(kt) * 64u), d_);                \
    load_lds16(Bt + (boff[hh][1] + (u32)(kt) * 64u), d_ + 512);          \
  } while (0)
#define RD4(dst, base)                                                   \
  do {                                                                   \
    const u16* p_ = &lds[(base)];                                        \
    dst[0] = *(const bf16x8*)(p_);                                       \
    dst[1] = *(const bf16x8*)(p_ + 1024);                                \
    dst[2] = *(const bf16x8*)(p_ + 2048);                                \
    dst[3] = *(const bf16x8*)(p_ + 3072);                                \
  } while (0)
#define BAR __builtin_amdgcn_s_barrier()
#define LGKM0 asm volatile("s_waitcnt lgkmcnt(0)" ::: "memory")
#define LGKM8 asm volatile("s_waitcnt lgkmcnt(8)" ::: "memory")
#define VM6 asm volatile("s_waitcnt vmcnt(6)" ::: "memory")
#define PRIO1 __builtin_amdgcn_s_setprio(1)
#define PRIO0 __builtin_amdgcn_s_setprio(0)

  // ---- prologue: stage tile0 {B0,B1,A0,A1} + tile1 {B0,B1,A0}; keep 3 in flight
  STG_B(0, 0, 0);
  STG_B(0, 1, 0);
  STG_A(0, 0, 0);
  STG_A(0, 1, 0);
  STG_B(1, 0, 1);
  STG_B(1, 1, 1);
  STG_A(1, 0, 1);
  VM6;   // tile0 fully resident; tile1 {B0,B1,A0} in flight
  BAR;

  bf16x8 Bf0[4], Bf1[4], Af0[4], Af1[4];

  for (int i = 0; i < (nt >> 1); ++i) {
    const int tb = 2 * i + 1;
    int t2 = 2 * i + 2; if (t2 >= nt) t2 -= nt;   // wrapped tail stages are
    int t3 = 2 * i + 3; if (t3 >= nt) t3 -= nt;   // garbage-but-harmless

    // ======== group 1: tile 2i from buf0 ========
    // P1: reads 12 (all B kk0+kk1, A m0-3 kk0); stage tb.A1 -> buf1.A1
    RD4(Bf0, bR);
    RD4(Bf1, bR ^ 32u);
    RD4(Af0, aR);
    STG_A(1, 1, tb);
    LGKM8;
    BAR; LGKM0;
    PRIO1; mm16<0>(acc, Af0, Bf0); PRIO0;
    BAR;
    // P2: reads A m4-7 kk0; stage t2.B0 -> buf0.B0 (B reads all done in P1)
    RD4(Af1, aR + 4096u);
    STG_B(0, 0, t2);
    BAR; LGKM0;
    PRIO1; mm16<4>(acc, Af1, Bf0); PRIO0;
    BAR;
    // P3: reads A m0-7 kk1; stage t2.B1 -> buf0.B1
    RD4(Af0, aR ^ 32u);
    RD4(Af1, (aR + 4096u) ^ 32u);
    STG_B(0, 1, t2);
    BAR; LGKM0;
    PRIO1; mm16<0>(acc, Af0, Bf1); PRIO0;
    BAR;
    // P4: no reads; stage t2.A0 -> buf0.A0 (A reads done by P3); counted vmcnt
    STG_A(0, 0, t2);
    VM6;  // retires tile tb completely (B0,B1,A0,A1); t2 {B0,B1,A0} in flight
    BAR;
    PRIO1; mm16<4>(acc, Af1, Bf1); PRIO0;
    BAR;

    // ======== group 2: tile 2i+1 from buf1 ========
    // P5
    RD4(Bf0, 32768u + bR);
    RD4(Bf1, (32768u + bR) ^ 32u);
    RD4(Af0, 32768u + aR);
    STG_A(0, 1, t2);
    LGKM8;
    BAR; LGKM0;
    PRIO1; mm16<0>(acc, Af0, Bf0); PRIO0;
    BAR;
    // P6
    RD4(Af1, 32768u + aR + 4096u);
    STG_B(1, 0, t3);
    BAR; LGKM0;
    PRIO1; mm16<4>(acc, Af1, Bf0); PRIO0;
    BAR;
    // P7
    RD4(Af0, (32768u + aR) ^ 32u);
    RD4(Af1, (32768u + aR + 4096u) ^ 32u);
    STG_B(1, 1, t3);
    BAR; LGKM0;
    PRIO1; mm16<0>(acc, Af0, Bf1); PRIO0;
    BAR;
    // P8
    STG_A(1, 0, t3);
    VM6;  // retires tile t2 completely; t3 {B0,B1,A0} in flight
    BAR;
    PRIO1; mm16<4>(acc, Af1, Bf1); PRIO0;
    BAR;
  }

  asm volatile("s_waitcnt vmcnt(0)" ::: "memory");  // drain wrapped tail stages

#undef STG_A
#undef STG_B
#undef RD4
#undef BAR
#undef LGKM0
#undef LGKM8
#undef VM6
#undef PRIO1
#undef PRIO0

  const int rb0 = m0 + wm * 128 + q * 4;
  const int cb0 = n0 + wn * 64 + c;
#pragma unroll
  for (int mf = 0; mf < 8; ++mf)
#pragma unroll
    for (int nf = 0; nf < 4; ++nf) {
      const size_t base = (size_t)(rb0 + mf * 16) * N + (cb0 + nf * 16);
#pragma unroll
      for (int r = 0; r < 4; ++r) {
        if (OUT_BF16)
          ((u16*)Cout)[base + (size_t)r * N] = f2bf(acc[mf][nf][r]);
        else
          ((float*)Cout)[base + (size_t)r * N] = acc[mf][nf][r];
      }
    }
}

// ---------------------------------------------------------------- qkv postprocess
__global__ __launch_bounds__(256) void qkv_post(const u16* __restrict__ raw,
                                                u16* __restrict__ qb,
                                                u16* __restrict__ kb,
                                                u16* __restrict__ vb) {
  const int t = threadIdx.x, lane = t & 63, w = t >> 6;
  const int idx = blockIdx.x * 4 + w;
  const int row = idx / 48, hh = idx - row * 48;
  const int b = row >> 11, pos = row & 2047;
  const u16* base = raw + (size_t)row * 6144 + hh * 128;
  const u16 r1 = base[lane], r2 = base[lane + 64];

  if (hh >= 40) {
    u16* dst = vb + ((size_t)((b * 8 + (hh - 40)) * 2048 + pos)) * 128;
    dst[lane] = r1;
    dst[lane + 64] = r2;
    return;
  }
  float v1 = bf2f(r1), v2 = bf2f(r2);
  float ss = v1 * v1 + v2 * v2;
#pragma unroll
  for (int off = 32; off >= 1; off >>= 1) ss += __shfl_xor(ss, off);
  const float rn = rsqrtf(ss * (1.0f / 128.0f) + 1e-6f);
  const float n1 = v1 * rn, n2 = v2 * rn;
  const float fr = exp2f(-(float)lane * 0.20762050593046f);  // 10000^(-lane/64)
  const float ang = (float)pos * fr;
  float sn, cs;
  sincosf(ang, &sn, &cs);
  float o1 = n1 * cs - n2 * sn;
  float o2 = n2 * cs + n1 * sn;
  u16* dst;
  if (hh < 32) {
    const float as_ = logf(floorf((float)(pos + 1) * (1.0f / 8192.0f)) + 1.0f) * 0.1f + 1.0f;
    const float sc = 0.088388347648318447f * as_;  // 128^-0.5 * attn_scale
    o1 *= sc;
    o2 *= sc;
    dst = qb + ((size_t)((b * 32 + hh) * 2048 + pos)) * 128;
  } else {
    dst = kb + ((size_t)((b * 8 + (hh - 32)) * 2048 + pos)) * 128;
  }
  dst[lane] = f2bf(o1);
  dst[lane + 64] = f2bf(o2);
}

// ---------------------------------------------------------------- flash attention
// Block: one (b, hq, 64-query tile); 4 waves; each wave owns 16 queries.
// R8: KVBLK=32, double-buffered K/V (36KB LDS total -> 4 blocks/CU).
// Per tile: stage next tile into buf^1, compute QK^T/softmax/PV from
// buf[cur], ONE __syncthreads (drains stage + WAR guard). Slot swizzle for
// 4-slot (64B) rows: phys = logical ^ (r&3)^((r>>2)&3); K rows (256B, 16
// slots) keep the R6 scheme phys = logical ^ (row&15).
__global__ __launch_bounds__(256, 4) void attn_fwd(const u16* __restrict__ qb,
                                                   const u16* __restrict__ kb,
                                                   const u16* __restrict__ vtb,
                                                   u16* __restrict__ attn) {
  __shared__ __align__(16) u16 Ks[2][32 * 128];   // [buf][key][d]   16KB
  __shared__ __align__(16) u16 VTs[2][128 * 32];  // [buf][d][key]   16KB
  __shared__ __align__(16) u16 Ps[4][16 * 32];    // per-wave [q][k]  4KB

  const int t = threadIdx.x, lane = t & 63, w = t >> 6;
  const int c = lane & 15, quad = lane >> 4;
  const int swzc = (c & 3) ^ ((c >> 2) & 3);  // 4-slot swizzle for row index c
  // XCD-contiguous q-tile mapping: 32 x-blocks = 8 XCDs x 4 contiguous tiles
  const int bxr = (int)blockIdx.x;
  const int q0 = ((bxr & 7) * 4 + (bxr >> 3)) * 64;
  const int bh = blockIdx.y;
  const int b = bh >> 5, hq = bh & 31;
  const int kvp = b * 8 + (hq >> 2);
  const u16* qp = qb + (size_t)bh * (2048 * 128);
  const u16* kp = kb + (size_t)kvp * (2048 * 128);
  const u16* vp = vtb + (size_t)kvp * (128 * 2048);
  u16* Psw = &Ps[w][0];

  bf16x8 qf[4];
  {
    const u16* qrow = qp + (size_t)(q0 + w * 16 + c) * 128 + quad * 8;
#pragma unroll
    for (int ks = 0; ks < 4; ++ks) qf[ks] = *(const bf16x8*)(qrow + ks * 32);
  }

  f32x4 oacc[8];
#pragma unroll
  for (int j = 0; j < 8; ++j)
#pragma unroll
    for (int r = 0; r < 4; ++r) oacc[j][r] = 0.0f;
  float lsum = 0.0f;

  const int i_glob = q0 + w * 16 + c;

  int t0 = q0 - 1023;
  if (t0 < 0) t0 = 0;
  t0 = (t0 >> 5) << 5;
  const int last = q0 + 32;  // final kv0 (covers keys [q0+32, q0+64))

  // stage one 32-key tile into buffer nb: K 8KB (2 loads/wave) + V 8KB (2)
#define STAGE_KV(nb, kvbase)                                                   \
  do {                                                                         \
    _Pragma("unroll")                                                          \
    for (int i_ = 0; i_ < 2; ++i_) {                                           \
      const int row_ = w * 4 + i_ * 16 + (lane >> 4);                          \
      const int g_ = (lane & 15) ^ (row_ & 15);                                \
      load_lds16(kp + (size_t)((kvbase) + row_) * 128 + g_ * 8,                \
                 &Ks[nb][(w * 4 + i_ * 16) * 128]);                            \
    }                                                                          \
    const int gv_ = (lane & 3) ^ ((lane >> 2) & 3) ^ ((lane >> 4) & 3);        \
    _Pragma("unroll")                                                          \
    for (int i_ = 0; i_ < 2; ++i_) {                                           \
      const int dd_ = w * 16 + i_ * 64 + (lane >> 2);                          \
      load_lds16(vp + (size_t)dd_ * 2048 + (kvbase) + gv_ * 8,                 \
                 &VTs[nb][(w * 16 + i_ * 64) * 32]);                           \
    }                                                                          \
  } while (0)

  // prologue: stage first tile into buf0
  STAGE_KV(0, t0);
  __syncthreads();

  int cur = 0;
  for (int kv0 = t0; kv0 <= last; kv0 += 32) {
    if (kv0 + 32 <= last) STAGE_KV(cur ^ 1, kv0 + 32);

    const u16* Kc = &Ks[cur][0];
    const u16* Vc = &VTs[cur][0];

    // ---- S^T = K * Q^T : wave computes 32 keys x 16 queries
    f32x4 sacc[2];
#pragma unroll
    for (int im = 0; im < 2; ++im)
#pragma unroll
      for (int r = 0; r < 4; ++r) sacc[im][r] = 0.0f;

#pragma unroll
    for (int ks = 0; ks < 4; ++ks) {
#pragma unroll
      for (int im = 0; im < 2; ++im) {
        const int key = im * 16 + c;
        const int ch = (ks * 4 + quad) ^ c;  // key & 15 == c
        const bf16x8 af = *(const bf16x8*)&Kc[key * 128 + ch * 8];
        sacc[im] = __builtin_amdgcn_mfma_f32_16x16x32_bf16(af, qf[ks], sacc[im], 0, 0, 0);
      }
    }

    // mask iff tile straddles the diagonal or the window edge
    const bool need_mask = (kv0 > q0 - 32) || (kv0 <= q0 - 961);
#pragma unroll
    for (int im = 0; im < 2; ++im) {
      float pv[4];
#pragma unroll
      for (int r = 0; r < 4; ++r) {
        const float s = sacc[im][r];
        const float u = s * s;
        // 50*tanh(s/50) = s*(1 - u/7500 + 2u^2/9.375e7), |s|<=11.4
        const float cap = s * (1.0f + u * (-1.3333333e-4f + u * 2.1333333e-8f));
        pv[r] = __expf(cap);
      }
      if (need_mask) {
        const int j_base = kv0 + im * 16 + quad * 4;
#pragma unroll
        for (int r = 0; r < 4; ++r) {
          const int j_glob = j_base + r;
          if (!((j_glob <= i_glob) && (i_glob - j_glob < 1024))) pv[r] = 0.0f;
        }
      }
      lsum += (pv[0] + pv[1]) + (pv[2] + pv[3]);
      // keys im*16+quad*4+{0..3} of query c -> logical slot im*2+(quad>>1),
      // half = quad&1; phys slot = logical ^ swzc
      uint2 pk;
      pk.x = pack_trunc(pv[0], pv[1]);
      pk.y = pack_trunc(pv[2], pv[3]);
      *(uint2*)&Psw[c * 32 + (((im * 2 + (quad >> 1)) ^ swzc)) * 8 + (quad & 1) * 4] = pk;
    }

    // ---- PV: A-frag = P[c][quad*8..+7] (phys slot quad^swzc); K=32 exact
    {
      const bf16x8 pf = *(const bf16x8*)&Psw[c * 32 + ((quad ^ swzc)) * 8];
#pragma unroll
      for (int jn = 0; jn < 8; ++jn) {
        const int dd = jn * 16 + c;
        // swz(dd) = (dd&3)^((dd>>2)&3) = swzc  (jn*16 contributes 0 mod 4)
        const bf16x8 vf = *(const bf16x8*)&Vc[dd * 32 + ((quad ^ swzc)) * 8];
        oacc[jn] = __builtin_amdgcn_mfma_f32_16x16x32_bf16(pf, vf, oacc[jn], 0, 0, 0);
      }
    }

    __syncthreads();  // drains next-tile stage; buf[cur] reads retired
    cur ^= 1;
  }
#undef STAGE_KV

  // ---- normalize + store (cross-quad shuffle reduce; no LDS)
  float lt = lsum;
  lt += __shfl_xor(lt, 16);
  lt += __shfl_xor(lt, 32);       // all lanes: total for query c
  float rl[4];
#pragma unroll
  for (int r = 0; r < 4; ++r)
    rl[r] = __builtin_amdgcn_rcpf(__shfl(lt, quad * 4 + r));

  const size_t obase = ((size_t)(b * 2048 + q0 + w * 16)) * 4096 + hq * 128;
#pragma unroll
  for (int jn = 0; jn < 8; ++jn) {
#pragma unroll
    for (int r = 0; r < 4; ++r) {
      const int q_in = quad * 4 + r;
      attn[obase + (size_t)q_in * 4096 + jn * 16 + c] = f2bf(oacc[jn][r] * rl[r]);
    }
  }
}

// ---------------------------------------------------------------- launch
extern "C" void kernel_launch(void* const* d_in, const int* in_sizes, int n_in,
                              void* d_out, int out_size, void* d_ws, size_t ws_size,
                              hipStream_t stream) {
  (void)in_sizes; (void)n_in; (void)out_size; (void)ws_size;
  const float* x  = (const float*)d_in[0];
  const float* Wq = (const float*)d_in[1];
  const float* Wk = (const float*)d_in[2];
  const float* Wv = (const float*)d_in[3];
  const float* Wo = (const float*)d_in[4];
  float* out = (float*)d_out;
  char* ws = (char*)d_ws;

  u16* xb    = (u16*)(ws + 0);
  u16* vtb   = (u16*)(ws + 0);
  u16* WqkvT = (u16*)(ws + 33554432ULL);
  u16* qb    = (u16*)(ws + 33554432ULL);
  u16* kb    = (u16*)(ws + 67108864ULL);
  u16* vb    = (u16*)(ws + 75497472ULL);
  u16* WoT   = (u16*)(ws + 83886080ULL);
  u16* qkvr  = (u16*)(ws + 117440512ULL);
  u16* attnb = (u16*)(ws + 117440512ULL);

  cast_f32_bf16<<<8192, 256, 0, stream>>>(x, xb);
  transpose_cast_f32_bf16<<<dim3(128, 128), 256, 0, stream>>>(Wq, WqkvT, 4096, 4096);
  transpose_cast_f32_bf16<<<dim3(32, 128), 256, 0, stream>>>(Wk, WqkvT + (size_t)4096 * 4096, 4096, 1024);
  transpose_cast_f32_bf16<<<dim3(32, 128), 256, 0, stream>>>(Wv, WqkvT + (size_t)5120 * 4096, 4096, 1024);
  transpose_cast_f32_bf16<<<dim3(128, 128), 256, 0, stream>>>(Wo, WoT, 4096, 4096);

  // QKV: M=4096, N=6144, K=4096 -> 16x24 = 384 tiles (384 % 8 == 0)
  gemm256<1><<<dim3(384), 512, 0, stream>>>(xb, WqkvT, (void*)qkvr, 6144, 4096, 24);
  qkv_post<<<49152, 256, 0, stream>>>(qkvr, qb, kb, vb);
  transpose_v<<<dim3(64, 4, 16), 256, 0, stream>>>(vb, vtb);
  attn_fwd<<<dim3(32, 64), 256, 0, stream>>>(qb, kb, vtb, attnb);
  // Out: M=4096, N=4096, K=4096 -> 16x16 = 256 tiles (256 % 8 == 0)
  gemm256<0><<<dim3(256), 512, 0, stream>>>(attnb, WoT, (void*)out, 4096, 4096, 16);
}

// Round 5
// 691.301 us; speedup vs baseline: 1.0490x; 1.0449x over previous
//
#include <hip/hip_runtime.h>

// Fused GQA attention layer for MI355X (gfx950).
// B=2 S=2048 E=4096 HQ=32 HKV=8 D=128 WINDOW=1024 SOFT_CAP=50 Q_PRE_ATTN=128
//
// R9: prep-chain vectorization + attn revert-to-best:
//   * qkv_post: 16B/lane (was 2B/lane scalar); 16-lane-group rmsnorm; RoPE
//     partner via shfl_xor(packed,8); attn_scale==1 folded (S=2048 < 8192).
//     V-branch removed.
//   * transpose_v reads V directly from qkvr (vb buffer + 32MB traffic gone).
//   * all transpose kernels: 8B/lane widened stores (was 2B/lane).
//   * attn_fwd: exact R6 revert (best measured: 710us config). R7/R8 attn
//     experiments were neutral -> attn not stage-latency-bound at 4 blk/CU.
//   * gemm256 unchanged (measured-stable 227us across R6/R7/R8).
//
// Workspace layout (160 MiB, regions reused over time):
//   [0,        33.5M)  xb        -> later vtb
//   [33.5M,    83.9M)  WqkvT     -> later qb|kb
//   [83.9M,   117.4M)  WoT       (persistent)
//   [117.4M,  167.8M)  qkv_raw   -> later attn

typedef unsigned short u16;
typedef unsigned int   u32;
typedef __bf16 bf16x8 __attribute__((ext_vector_type(8)));
typedef float  f32x4  __attribute__((ext_vector_type(4)));

typedef __attribute__((address_space(1))) void* gas_ptr;
typedef __attribute__((address_space(3))) void* las_ptr;

__device__ __forceinline__ void load_lds16(const void* g, void* l) {
  __builtin_amdgcn_global_load_lds((gas_ptr)g, (las_ptr)l, 16, 0, 0);
}

__device__ __forceinline__ u16 f2bf(float f) {
  u32 u = __builtin_bit_cast(u32, f);
  u += 0x7fffu + ((u >> 16) & 1u);   // RNE
  return (u16)(u >> 16);
}
__device__ __forceinline__ float bf2f(u16 h) {
  u32 u = ((u32)h) << 16;
  return __builtin_bit_cast(float, u);
}
// truncate-pack two fp32 -> bf16 pair (low = a, high = b)
__device__ __forceinline__ u32 pack_trunc(float a, float b) {
  return (__builtin_bit_cast(u32, a) >> 16) | (__builtin_bit_cast(u32, b) & 0xffff0000u);
}

// ---------------------------------------------------------------- cast x
__global__ __launch_bounds__(256) void cast_f32_bf16(const float* __restrict__ src,
                                                     u16* __restrict__ dst) {
  size_t i = ((size_t)blockIdx.x * 256 + threadIdx.x) * 8;
  float4 a = *(const float4*)(src + i);
  float4 b = *(const float4*)(src + i + 4);
  uint4 o;
  o.x = (u32)f2bf(a.x) | ((u32)f2bf(a.y) << 16);
  o.y = (u32)f2bf(a.z) | ((u32)f2bf(a.w) << 16);
  o.z = (u32)f2bf(b.x) | ((u32)f2bf(b.y) << 16);
  o.w = (u32)f2bf(b.z) | ((u32)f2bf(b.w) << 16);
  *(uint4*)(dst + i) = o;
}

// ------------------------------------------------- transpose-cast fp32->bf16
// dst[C][R] = cast(src[R][C]); 8B/lane stores (u16x4).
__global__ __launch_bounds__(256) void transpose_cast_f32_bf16(
    const float* __restrict__ src, u16* __restrict__ dst, int R, int C) {
  __shared__ float tile[32][33];
  const int tx = threadIdx.x & 31, ty = threadIdx.x >> 5;
  const int r0 = blockIdx.y * 32, c0 = blockIdx.x * 32;
#pragma unroll
  for (int i = 0; i < 4; ++i)
    tile[ty + i * 8][tx] = src[(size_t)(r0 + ty + i * 8) * C + (c0 + tx)];
  __syncthreads();
  uint2 ov;
  ov.x = (u32)f2bf(tile[ty * 4 + 0][tx]) | ((u32)f2bf(tile[ty * 4 + 1][tx]) << 16);
  ov.y = (u32)f2bf(tile[ty * 4 + 2][tx]) | ((u32)f2bf(tile[ty * 4 + 3][tx]) << 16);
  *(uint2*)&dst[(size_t)(c0 + tx) * R + (r0 + ty * 4)] = ov;
}

// ------------------------------------------------- V plane transpose from qkvr
// vtb[plane][d][pos] = qkvr[(b,pos)][(40+h8)*128 + d]; plane = b*8+h8.
__global__ __launch_bounds__(256) void transpose_v(const u16* __restrict__ qkvr,
                                                   u16* __restrict__ vtb) {
  __shared__ u16 tile[32][34];
  const int plane = blockIdx.z;
  const int b = plane >> 3, h8 = plane & 7;
  const u16* s = qkvr + (size_t)(b * 2048) * 6144 + (40 + h8) * 128;
  u16* d = vtb + (size_t)plane * 2048 * 128;
  const int tx = threadIdx.x & 31, ty = threadIdx.x >> 5;
  const int r0 = blockIdx.x * 32, c0 = blockIdx.y * 32;   // r=pos, c=d
#pragma unroll
  for (int i = 0; i < 4; ++i)
    tile[ty + i * 8][tx] = s[(size_t)(r0 + ty + i * 8) * 6144 + (c0 + tx)];
  __syncthreads();
  uint2 ov;
  ov.x = (u32)tile[ty * 4 + 0][tx] | ((u32)tile[ty * 4 + 1][tx] << 16);
  ov.y = (u32)tile[ty * 4 + 2][tx] | ((u32)tile[ty * 4 + 3][tx] << 16);
  *(uint2*)&d[(size_t)(c0 + tx) * 2048 + (r0 + ty * 4)] = ov;
}

// ---------------------------------------------------------------- GEMM 256^2 8-phase
// C[M][N] = A[M][K] @ Bt[N][K]^T. Requires: M%256==0, N%256==0, K%128==0,
// grid = (M/256)*(N/256) with grid%8==0.
// LDS (u16 idx): buf b at b*32768; A-half h at +h*8192; B-half h at +16384+h*8192.
// Half-tile = 128 rows x 64 cols bf16, row = 64 u16; slot = 8 u16 (16B);
// physical slot = logical slot ^ (row & 7).

template <int MB>
__device__ __forceinline__ void mm16(f32x4 (&acc)[8][4], const bf16x8 (&af)[4],
                                     const bf16x8 (&bf)[4]) {
#pragma unroll
  for (int ii = 0; ii < 4; ++ii)
#pragma unroll
    for (int nf = 0; nf < 4; ++nf)
      acc[MB + ii][nf] =
          __builtin_amdgcn_mfma_f32_16x16x32_bf16(af[ii], bf[nf], acc[MB + ii][nf], 0, 0, 0);
}

template <int OUT_BF16>
__global__ __launch_bounds__(512, 2) void gemm256(const u16* __restrict__ A,
                                                  const u16* __restrict__ Bt,
                                                  void* __restrict__ Cout,
                                                  int N, int K, int ntx) {
  __shared__ __align__(16) u16 lds[65536];   // 128 KiB
  const int t = threadIdx.x, lane = t & 63, w = t >> 6;
  const int c = lane & 15, q = lane >> 4;
  const int wm = w >> 2, wn = w & 3;         // 2 x 4 wave grid, per-wave 128x64

  // bijective XCD swizzle (grid % 8 == 0)
  const int cpx = (int)gridDim.x >> 3;
  const int swz = ((int)blockIdx.x & 7) * cpx + ((int)blockIdx.x >> 3);
  const int bx = swz % ntx, by = swz / ntx;
  const int m0 = by << 8, n0 = bx << 8;

  u32 aoff[2][2], boff[2][2];
#pragma unroll
  for (int h = 0; h < 2; ++h)
#pragma unroll
    for (int j = 0; j < 2; ++j) {
      const int rowS = w * 16 + j * 8 + (lane >> 3);
      const int colE = ((lane & 7) ^ (rowS & 7)) * 8;
      aoff[h][j] = (u32)(m0 + h * 128 + rowS) * (u32)K + (u32)colE;
      boff[h][j] = (u32)(n0 + h * 128 + rowS) * (u32)K + (u32)colE;
    }
  const u32 stW = (u32)w * 1024u;

  const u32 sl0 = (u32)((q ^ (c & 7)) * 8);
  const u32 aR = (u32)(wm * 8192 + c * 64) + sl0;
  const u32 bR = (u32)(16384 + (wn >> 1) * 8192 + (wn & 1) * 4096 + c * 64) + sl0;

  f32x4 acc[8][4];
#pragma unroll
  for (int i2 = 0; i2 < 8; ++i2)
#pragma unroll
    for (int j2 = 0; j2 < 4; ++j2) acc[i2][j2] = (f32x4){0.f, 0.f, 0.f, 0.f};

  const int nt = K >> 6;

#define STG_A(bb, hh, kt)                                                \
  do {                                                                   \
    u16* d_ = &lds[(bb) * 32768u + (hh) * 8192u + stW];                  \
    load_lds16(A + (aoff[hh][0] + (u32)(kt) * 64u), d_);                 \
    load_lds16(A + (aoff[hh][1] + (u32)(kt) * 64u), d_ + 512);           \
  } while (0)
#define STG_B(bb, hh, kt)                                                \
  do {                                                                   \
    u16* d_ = &lds[(bb) * 32768u + 16384u + (hh) * 8192u + stW];         \
    load_lds16(Bt + (boff[hh][0] + (u32)(kt) * 64u), d_);                \
    load_lds16(Bt + (boff[hh][1] + (u32)(kt) * 64u), d_ + 512);          \
  } while (0)
#define RD4(dst, base)                                                   \
  do {                                                                   \
    const u16* p_ = &lds[(base)];                                        \
    dst[0] = *(const bf16x8*)(p_);                                       \
    dst[1] = *(const bf16x8*)(p_ + 1024);                                \
    dst[2] = *(const bf16x8*)(p_ + 2048);                                \
    dst[3] = *(const bf16x8*)(p_ + 3072);                                \
  } while (0)
#define BAR __builtin_amdgcn_s_barrier()
#define LGKM0 asm volatile("s_waitcnt lgkmcnt(0)" ::: "memory")
#define LGKM8 asm volatile("s_waitcnt lgkmcnt(8)" ::: "memory")
#define VM6 asm volatile("s_waitcnt vmcnt(6)" ::: "memory")
#define PRIO1 __builtin_amdgcn_s_setprio(1)
#define PRIO0 __builtin_amdgcn_s_setprio(0)

  STG_B(0, 0, 0);
  STG_B(0, 1, 0);
  STG_A(0, 0, 0);
  STG_A(0, 1, 0);
  STG_B(1, 0, 1);
  STG_B(1, 1, 1);
  STG_A(1, 0, 1);
  VM6;
  BAR;

  bf16x8 Bf0[4], Bf1[4], Af0[4], Af1[4];

  for (int i = 0; i < (nt >> 1); ++i) {
    const int tb = 2 * i + 1;
    int t2 = 2 * i + 2; if (t2 >= nt) t2 -= nt;
    int t3 = 2 * i + 3; if (t3 >= nt) t3 -= nt;

    // ======== group 1: tile 2i from buf0 ========
    RD4(Bf0, bR);
    RD4(Bf1, bR ^ 32u);
    RD4(Af0, aR);
    STG_A(1, 1, tb);
    LGKM8;
    BAR; LGKM0;
    PRIO1; mm16<0>(acc, Af0, Bf0); PRIO0;
    BAR;
    RD4(Af1, aR + 4096u);
    STG_B(0, 0, t2);
    BAR; LGKM0;
    PRIO1; mm16<4>(acc, Af1, Bf0); PRIO0;
    BAR;
    RD4(Af0, aR ^ 32u);
    RD4(Af1, (aR + 4096u) ^ 32u);
    STG_B(0, 1, t2);
    BAR; LGKM0;
    PRIO1; mm16<0>(acc, Af0, Bf1); PRIO0;
    BAR;
    STG_A(0, 0, t2);
    VM6;
    BAR;
    PRIO1; mm16<4>(acc, Af1, Bf1); PRIO0;
    BAR;

    // ======== group 2: tile 2i+1 from buf1 ========
    RD4(Bf0, 32768u + bR);
    RD4(Bf1, (32768u + bR) ^ 32u);
    RD4(Af0, 32768u + aR);
    STG_A(0, 1, t2);
    LGKM8;
    BAR; LGKM0;
    PRIO1; mm16<0>(acc, Af0, Bf0); PRIO0;
    BAR;
    RD4(Af1, 32768u + aR + 4096u);
    STG_B(1, 0, t3);
    BAR; LGKM0;
    PRIO1; mm16<4>(acc, Af1, Bf0); PRIO0;
    BAR;
    RD4(Af0, (32768u + aR) ^ 32u);
    RD4(Af1, (32768u + aR + 4096u) ^ 32u);
    STG_B(1, 1, t3);
    BAR; LGKM0;
    PRIO1; mm16<0>(acc, Af0, Bf1); PRIO0;
    BAR;
    STG_A(1, 0, t3);
    VM6;
    BAR;
    PRIO1; mm16<4>(acc, Af1, Bf1); PRIO0;
    BAR;
  }

  asm volatile("s_waitcnt vmcnt(0)" ::: "memory");

#undef STG_A
#undef STG_B
#undef RD4
#undef BAR
#undef LGKM0
#undef LGKM8
#undef VM6
#undef PRIO1
#undef PRIO0

  const int rb0 = m0 + wm * 128 + q * 4;
  const int cb0 = n0 + wn * 64 + c;
#pragma unroll
  for (int mf = 0; mf < 8; ++mf)
#pragma unroll
    for (int nf = 0; nf < 4; ++nf) {
      const size_t base = (size_t)(rb0 + mf * 16) * N + (cb0 + nf * 16);
#pragma unroll
      for (int r = 0; r < 4; ++r) {
        if (OUT_BF16)
          ((u16*)Cout)[base + (size_t)r * N] = f2bf(acc[mf][nf][r]);
        else
          ((float*)Cout)[base + (size_t)r * N] = acc[mf][nf][r];
      }
    }
}

// ---------------------------------------------------------------- qkv postprocess
// Q/K only (V handled by transpose_v). One head-row (128 bf16 = 256B) per
// 16-lane group; 16B/lane. rmsnorm via 16-lane shfl; RoPE partner (d <-> d+64)
// is lane c^8 (4 shfl_xor on packed bf16). attn_scale == 1 for S=2048.
__global__ __launch_bounds__(256) void qkv_post(const u16* __restrict__ raw,
                                                u16* __restrict__ qb,
                                                u16* __restrict__ kb) {
  const int t = threadIdx.x;
  const int c = t & 15, g = t >> 4;
  const u32 u = (u32)blockIdx.x * 16u + (u32)g;   // u < 163840
  const u32 row = u / 40u;
  const int hh = (int)(u - row * 40u);            // 0..39 (q:0-31, k:32-39)
  const int pos = (int)(row & 2047u);
  const int b = (int)(row >> 11);

  const uint4 rv = *(const uint4*)(raw + (size_t)row * 6144 + hh * 128 + c * 8);
  u32 rw[4] = {rv.x, rv.y, rv.z, rv.w};
  float xs[8];
#pragma unroll
  for (int j = 0; j < 4; ++j) {
    xs[2 * j] = bf2f((u16)(rw[j] & 0xffffu));
    xs[2 * j + 1] = bf2f((u16)(rw[j] >> 16));
  }
  float ss = 0.f;
#pragma unroll
  for (int j = 0; j < 8; ++j) ss += xs[j] * xs[j];
#pragma unroll
  for (int off = 8; off >= 1; off >>= 1) ss += __shfl_xor(ss, off);
  const float rn = rsqrtf(ss * (1.0f / 128.0f) + 1e-6f);

  u32 pw[4];
#pragma unroll
  for (int j = 0; j < 4; ++j) pw[j] = __shfl_xor(rw[j], 8);
  float xp[8];
#pragma unroll
  for (int j = 0; j < 4; ++j) {
    xp[2 * j] = bf2f((u16)(pw[j] & 0xffffu));
    xp[2 * j + 1] = bf2f((u16)(pw[j] >> 16));
  }

  const float sgn = (c < 8) ? -1.0f : 1.0f;
  const int dbase = (c & 7) * 8;
  const float fpos = (float)pos;
  const bool isq = (hh < 32);
  const float sc = (isq ? 0.088388347648318447f : 1.0f) * rn;  // 128^-0.5 * 1
  float o[8];
#pragma unroll
  for (int j = 0; j < 8; ++j) {
    const float fr = exp2f(-(float)(dbase + j) * 0.20762050593046f);
    float sn, cs;
    sincosf(fpos * fr, &sn, &cs);
    o[j] = (xs[j] * cs + sgn * xp[j] * sn) * sc;
  }

  uint4 ov;
  ov.x = (u32)f2bf(o[0]) | ((u32)f2bf(o[1]) << 16);
  ov.y = (u32)f2bf(o[2]) | ((u32)f2bf(o[3]) << 16);
  ov.z = (u32)f2bf(o[4]) | ((u32)f2bf(o[5]) << 16);
  ov.w = (u32)f2bf(o[6]) | ((u32)f2bf(o[7]) << 16);
  u16* dst = isq ? (qb + ((size_t)((b * 32 + hh) * 2048 + pos)) * 128)
                 : (kb + ((size_t)((b * 8 + (hh - 32)) * 2048 + pos)) * 128);
  *(uint4*)(dst + c * 8) = ov;
}

// ---------------------------------------------------------------- flash attention
// Exact R6 revert (best measured): one (b,hq,64-query tile) per block; 4
// waves; single-buffered K/VT staging (40KB -> 4 blk/CU); 2 barriers/tile.
__global__ __launch_bounds__(256, 4) void attn_fwd(const u16* __restrict__ qb,
                                                   const u16* __restrict__ kb,
                                                   const u16* __restrict__ vtb,
                                                   u16* __restrict__ attn) {
  __shared__ __align__(16) u16 Ks[64 * 128];    // [key][d], chunk-swizzled (16 chunks)
  __shared__ __align__(16) u16 VTs[128 * 64];   // [d][key], chunk-swizzled (8 chunks)
  __shared__ __align__(16) u16 Ps[4][16 * 64];  // per-wave [query][key], chunk-swizzled

  const int t = threadIdx.x, lane = t & 63, w = t >> 6;
  const int c = lane & 15, quad = lane >> 4;
  const int q0 = blockIdx.x * 64;
  const int bh = blockIdx.y;
  const int b = bh >> 5, hq = bh & 31;
  const int kvp = b * 8 + (hq >> 2);
  const u16* qp = qb + (size_t)bh * (2048 * 128);
  const u16* kp = kb + (size_t)kvp * (2048 * 128);
  const u16* vp = vtb + (size_t)kvp * (128 * 2048);
  u16* Psw = &Ps[w][0];

  bf16x8 qf[4];
  {
    const u16* qrow = qp + (size_t)(q0 + w * 16 + c) * 128 + quad * 8;
#pragma unroll
    for (int ks = 0; ks < 4; ++ks) qf[ks] = *(const bf16x8*)(qrow + ks * 32);
  }

  f32x4 oacc[8];
#pragma unroll
  for (int j = 0; j < 8; ++j)
#pragma unroll
    for (int r = 0; r < 4; ++r) oacc[j][r] = 0.0f;
  float lsum = 0.0f;

  const int i_glob = q0 + w * 16 + c;

  int t0 = q0 - 1023;
  if (t0 < 0) t0 = 0;
  t0 = (t0 >> 6) << 6;

  for (int kv0 = t0; kv0 <= q0; kv0 += 64) {
    __syncthreads();  // previous iteration done reading Ks/VTs
    {
      const int row_in = lane >> 4, ch = lane & 15;
#pragma unroll
      for (int i = 0; i < 4; ++i) {
        const int row = w * 4 + i * 16 + row_in;
        const int g = ch ^ (row & 15);
        load_lds16(kp + (size_t)(kv0 + row) * 128 + g * 8, &Ks[(w * 4 + i * 16) * 128]);
      }
      const int drow = lane >> 3, ch8 = lane & 7;
#pragma unroll
      for (int i = 0; i < 4; ++i) {
        const int dd = w * 8 + i * 32 + drow;
        const int g = ch8 ^ (dd & 7);
        load_lds16(vp + (size_t)dd * 2048 + kv0 + g * 8, &VTs[(w * 8 + i * 32) * 64]);
      }
    }
    __syncthreads();  // staging complete

    f32x4 sacc[4];
#pragma unroll
    for (int im = 0; im < 4; ++im)
#pragma unroll
      for (int r = 0; r < 4; ++r) sacc[im][r] = 0.0f;

#pragma unroll
    for (int ks = 0; ks < 4; ++ks) {
#pragma unroll
      for (int im = 0; im < 4; ++im) {
        const int key = im * 16 + c;
        const int ch = (ks * 4 + quad) ^ c;  // key & 15 == c
        const bf16x8 af = *(const bf16x8*)&Ks[key * 128 + ch * 8];
        sacc[im] = __builtin_amdgcn_mfma_f32_16x16x32_bf16(af, qf[ks], sacc[im], 0, 0, 0);
      }
    }

    const bool need_mask = (kv0 == q0) || (q0 - kv0 >= 961);
#pragma unroll
    for (int im = 0; im < 4; ++im) {
      float pv[4];
#pragma unroll
      for (int r = 0; r < 4; ++r) {
        const float s = sacc[im][r];
        const float u = s * s;
        // 50*tanh(s/50) = s*(1 - u/7500 + 2u^2/9.375e7), |s|<=11.4
        const float cap = s * (1.0f + u * (-1.3333333e-4f + u * 2.1333333e-8f));
        pv[r] = __expf(cap);
      }
      if (need_mask) {
        const int j_base = kv0 + im * 16 + quad * 4;
#pragma unroll
        for (int r = 0; r < 4; ++r) {
          const int j_glob = j_base + r;
          if (!((j_glob <= i_glob) && (i_glob - j_glob < 1024))) pv[r] = 0.0f;
        }
      }
      lsum += (pv[0] + pv[1]) + (pv[2] + pv[3]);
      uint2 pk;
      pk.x = pack_trunc(pv[0], pv[1]);
      pk.y = pack_trunc(pv[2], pv[3]);
      *(uint2*)&Psw[c * 64 + ((im * 2 + (quad >> 1)) ^ (c & 7)) * 8 + (quad & 1) * 4] = pk;
    }

#pragma unroll
    for (int ks = 0; ks < 2; ++ks) {
      const bf16x8 pf = *(const bf16x8*)&Psw[c * 64 + ((ks * 4 + quad) ^ (c & 7)) * 8];
#pragma unroll
      for (int jn = 0; jn < 8; ++jn) {
        const int dd = jn * 16 + c;
        const int ch = (ks * 4 + quad) ^ (c & 7);  // dd & 7 == c & 7
        const bf16x8 vf = *(const bf16x8*)&VTs[dd * 64 + ch * 8];
        oacc[jn] = __builtin_amdgcn_mfma_f32_16x16x32_bf16(pf, vf, oacc[jn], 0, 0, 0);
      }
    }
  }

  float lt = lsum;
  lt += __shfl_xor(lt, 16);
  lt += __shfl_xor(lt, 32);
  float rl[4];
#pragma unroll
  for (int r = 0; r < 4; ++r)
    rl[r] = __builtin_amdgcn_rcpf(__shfl(lt, quad * 4 + r));

  const size_t obase = ((size_t)(b * 2048 + q0 + w * 16)) * 4096 + hq * 128;
#pragma unroll
  for (int jn = 0; jn < 8; ++jn) {
#pragma unroll
    for (int r = 0; r < 4; ++r) {
      const int q_in = quad * 4 + r;
      attn[obase + (size_t)q_in * 4096 + jn * 16 + c] = f2bf(oacc[jn][r] * rl[r]);
    }
  }
}

// ---------------------------------------------------------------- launch
extern "C" void kernel_launch(void* const* d_in, const int* in_sizes, int n_in,
                              void* d_out, int out_size, void* d_ws, size_t ws_size,
                              hipStream_t stream) {
  (void)in_sizes; (void)n_in; (void)out_size; (void)ws_size;
  const float* x  = (const float*)d_in[0];
  const float* Wq = (const float*)d_in[1];
  const float* Wk = (const float*)d_in[2];
  const float* Wv = (const float*)d_in[3];
  const float* Wo = (const float*)d_in[4];
  float* out = (float*)d_out;
  char* ws = (char*)d_ws;

  u16* xb    = (u16*)(ws + 0);
  u16* vtb   = (u16*)(ws + 0);
  u16* WqkvT = (u16*)(ws + 33554432ULL);
  u16* qb    = (u16*)(ws + 33554432ULL);
  u16* kb    = (u16*)(ws + 67108864ULL);
  u16* WoT   = (u16*)(ws + 83886080ULL);
  u16* qkvr  = (u16*)(ws + 117440512ULL);
  u16* attnb = (u16*)(ws + 117440512ULL);

  cast_f32_bf16<<<8192, 256, 0, stream>>>(x, xb);
  transpose_cast_f32_bf16<<<dim3(128, 128), 256, 0, stream>>>(Wq, WqkvT, 4096, 4096);
  transpose_cast_f32_bf16<<<dim3(32, 128), 256, 0, stream>>>(Wk, WqkvT + (size_t)4096 * 4096, 4096, 1024);
  transpose_cast_f32_bf16<<<dim3(32, 128), 256, 0, stream>>>(Wv, WqkvT + (size_t)5120 * 4096, 4096, 1024);
  transpose_cast_f32_bf16<<<dim3(128, 128), 256, 0, stream>>>(Wo, WoT, 4096, 4096);

  // QKV: M=4096, N=6144, K=4096 -> 16x24 = 384 tiles (384 % 8 == 0)
  gemm256<1><<<dim3(384), 512, 0, stream>>>(xb, WqkvT, (void*)qkvr, 6144, 4096, 24);
  // Q/K rows: 4096 rows * 40 head-planes / 16 per block = 10240 blocks
  qkv_post<<<10240, 256, 0, stream>>>(qkvr, qb, kb);
  transpose_v<<<dim3(64, 4, 16), 256, 0, stream>>>(qkvr, vtb);
  attn_fwd<<<dim3(32, 64), 256, 0, stream>>>(qb, kb, vtb, attnb);
  // Out: M=4096, N=4096, K=4096 -> 16x16 = 256 tiles (256 % 8 == 0)
  gemm256<0><<<dim3(256), 512, 0, stream>>>(attnb, WoT, (void*)out, 4096, 4096, 16);
}